// Round 18
// baseline (30.155 us; speedup 1.0000x reference)
//
#include <hip/hip_runtime.h>
#include <math.h>

// Problem constants (from reference)
#define P_TOTAL 10000
#define G_TOTAL 6400
#define C_CLS   18
#define CS_SH   3                   // cell = 8 voxels = 4 m
#define NCX     25
#define NCELL   (NCX * NCX)         // 625
#define BCAP    256                 // boxes per cell (mean ~54, max ~150)
#define PCAP    96                  // points per cell (mean 16, max ~40)
#define NTHR    1024                // 16 waves per block (halves per-thread sweep chain)
#define HB      16                  // hits processed per batch (MLP width)

// Single fused kernel: block = cell. Vectorized sweeps, then wave-per-point
// gather with batched hit processing. R17 experiment: NTHR 512 -> 1024 to
// halve the per-thread dependent-iteration count in the sweep phases.
__global__ void __launch_bounds__(NTHR)
la_cell6(const float* __restrict__ pts,
         const float* __restrict__ means3D,
         const float* __restrict__ opacities,
         const float* __restrict__ semantics,
         const float* __restrict__ scales,
         const float* __restrict__ cov3D,
         float* __restrict__ out) {
    __shared__ int4 sbox[BCAP];     // 4 KB
    __shared__ int  splist[PCAP];
    __shared__ int  snb, snp;

    const int t = threadIdx.x;
    const int cell = blockIdx.x;
    const int ccx = cell % NCX;
    const int ccy = cell / NCX;

    if (t == 0) { snb = 0; snp = 0; }
    __syncthreads();

    // phase 1: collect this cell's points — 4 points per iteration (~2.4 iters)
    const float4* p4 = (const float4*)pts;
    for (int j = t; j < P_TOTAL / 4; j += NTHR) {
        float4 a = p4[j * 3 + 0];
        float4 b = p4[j * 3 + 1];
        float4 c = p4[j * 3 + 2];
        float pxs[4] = {a.x, a.w, b.z, c.y};
        float pys[4] = {a.y, b.x, b.w, c.z};
#pragma unroll
        for (int q = 0; q < 4; ++q) {
            int cx = ((int)((pxs[q] + 50.0f) * 2.0f)) >> CS_SH;
            int cy = ((int)((pys[q] + 50.0f) * 2.0f)) >> CS_SH;
            if (cx == ccx && cy == ccy) {
                int s = atomicAdd(&snp, 1);
                if (s < PCAP) splist[s] = j * 4 + q;
            }
        }
    }

    // phase 2: collect boxes overlapping this cell — 4 gaussians/iter (~1.6 iters)
    const float4* m4 = (const float4*)means3D;
    const float4* s4 = (const float4*)scales;
    for (int j = t; j < G_TOTAL / 4; j += NTHR) {
        float4 ma = m4[j * 3 + 0], mb = m4[j * 3 + 1], mc = m4[j * 3 + 2];
        float4 sa = s4[j * 3 + 0], sb = s4[j * 3 + 1], sc = s4[j * 3 + 2];
        float mxs[4] = {ma.x, ma.w, mb.z, mc.y};
        float mys[4] = {ma.y, mb.x, mb.w, mc.z};
        float mzs[4] = {ma.z, mb.y, mc.x, mc.w};
        float sxs[4] = {sa.x, sa.w, sb.z, sc.y};
        float sys[4] = {sa.y, sb.x, sb.w, sc.z};
        float szs[4] = {sa.z, sb.y, sc.x, sc.w};
#pragma unroll
        for (int q = 0; q < 4; ++q) {
            // (mu - PC_MIN)/0.5 == (mu - PC_MIN)*2 exactly
            int mix = (int)((mxs[q] + 50.0f) * 2.0f);
            int miy = (int)((mys[q] + 50.0f) * 2.0f);
            int miz = (int)((mzs[q] + 5.0f) * 2.0f);
            // radii = ceil(max(s)*3.0/0.5): *3.0 rounds, *2 exact
            int r = (int)ceilf((fmaxf(fmaxf(sxs[q], sys[q]), szs[q]) * 3.0f) * 2.0f);
            int w = 2 * r;
            int minx = mix - r, miny = miy - r, minz = miz - r;
            int cx0 = max(minx, 0) >> CS_SH;
            int cx1 = min(minx + w, 199) >> CS_SH;
            int cy0 = max(miny, 0) >> CS_SH;
            int cy1 = min(miny + w, 199) >> CS_SH;
            if (ccx >= cx0 && ccx <= cx1 && ccy >= cy0 && ccy <= cy1) {
                int s = atomicAdd(&snb, 1);
                if (s < BCAP)
                    sbox[s] = make_int4(minx, miny, minz, (w << 16) | (j * 4 + q));
            }
        }
    }
    __syncthreads();

    const int np = min(snp, PCAP);
    const int nb = min(snb, BCAP);
    const int wv = t >> 6, lane = t & 63;      // 16 waves per block

    // phase 3: wave-per-point gather; lanes 0..17 accumulate classes.
    for (int idx = wv; idx < np; idx += NTHR / 64) {
        int pt = splist[idx];
        float px = pts[pt * 3 + 0];
        float py = pts[pt * 3 + 1];
        float pz = pts[pt * 3 + 2];
        int pix = (int)((px + 50.0f) * 2.0f);
        int piy = (int)((py + 50.0f) * 2.0f);
        int piz = (int)((pz + 5.0f) * 2.0f);

        float acc = 0.0f;
        for (int base = 0; base < nb; base += 64) {
            int i = base + lane;
            float wgt = 0.0f;
            int gid = 0;
            if (i < nb) {
                int4 b = sbox[i];
                unsigned w  = ((unsigned)b.w) >> 16;
                unsigned ux = (unsigned)(pix - b.x);
                unsigned uy = (unsigned)(piy - b.y);
                unsigned uz = (unsigned)(piz - b.z);
                if (ux <= w && uy <= w && uz <= w) {
                    gid = b.w & 0xffff;
                    float mx = means3D[gid * 3 + 0];
                    float my = means3D[gid * 3 + 1];
                    float mz = means3D[gid * 3 + 2];
                    const float* cv = cov3D + (size_t)gid * 9;
                    float dx = px - mx, dy = py - my, dz = pz - mz;
                    float pw = -0.5f * (cv[0] * dx * dx + cv[4] * dy * dy + cv[8] * dz * dz)
                               - cv[1] * dx * dy - cv[5] * dy * dz - cv[2] * dx * dz;
                    wgt = __expf(pw) * opacities[gid];
                }
            }

            // batched hit processing: collect up to HB hits with shuffles only,
            // then issue all HB semantics loads independently (MLP ~13).
            unsigned long long m = __ballot(wgt != 0.0f);
            while (m) {
                float wh[HB];
                int   gh[HB];
#pragma unroll
                for (int k = 0; k < HB; ++k) {
                    bool has = (m != 0);
                    int h = (int)__builtin_ctzll(m | 0x8000000000000000ULL);
                    float w_ = __shfl(wgt, h, 64);   // uniform index -> readlane
                    int   g_ = __shfl(gid, h, 64);
                    wh[k] = has ? w_ : 0.0f;         // wgt=0 -> fma is identity
                    gh[k] = has ? g_ : 0;            // dummy load hits sem[0..17]
                    m &= m - 1;
                }
                if (lane < C_CLS) {
#pragma unroll
                    for (int k = 0; k < HB; ++k)
                        acc = fmaf(wh[k], semantics[(size_t)gh[k] * C_CLS + lane], acc);
                }
            }
        }

        if (lane < C_CLS)
            out[(size_t)pt * C_CLS + lane] = acc;   // coalesced 72B per point
    }
}

extern "C" void kernel_launch(void* const* d_in, const int* in_sizes, int n_in,
                              void* d_out, int out_size, void* d_ws, size_t ws_size,
                              hipStream_t stream) {
    const float* pts      = (const float*)d_in[0];
    const float* means3D  = (const float*)d_in[1];
    const float* opac     = (const float*)d_in[2];
    const float* sem      = (const float*)d_in[3];
    const float* scales   = (const float*)d_in[4];
    const float* cov3D    = (const float*)d_in[5];
    float* out = (float*)d_out;

    la_cell6<<<NCELL, NTHR, 0, stream>>>(pts, means3D, opac, sem, scales, cov3D, out);
}

// Round 19
// 28.216 us; speedup vs baseline: 1.0687x; 1.0687x over previous
//
#include <hip/hip_runtime.h>
#include <math.h>

// Problem constants (from reference)
#define P_TOTAL 10000
#define G_TOTAL 6400
#define C_CLS   18
#define CS_SH   3                   // cell = 8 voxels = 4 m
#define NCX     25
#define NCELL   (NCX * NCX)         // 625
#define BCAP    256                 // boxes per cell (mean ~54, max ~150)
#define PCAP    96                  // points per cell (mean 16, max ~40)
#define NTHR    512                 // 8 waves per block (empirically optimal: 1024 -> 30.2us, 512 -> 28.2us)
#define HB      16                  // hits processed per batch (MLP width)

// SESSION OPTIMUM (28.2 us, replicated x2). Single fused kernel: block = cell.
// Vectorized full-input sweeps (float4 x3, 4 elems/thread), then wave-per-point
// gather with BATCHED hit processing (collect hits via shuffles, then issue all
// semantics loads independently -> breaks the serial dependent-load chain).
// Falsified alternatives: cg::grid.sync (120us), resident spin barrier (97us),
// 3-node global binning (33-35us), supercell 2-level binning (62us, contended
// atomics), block-local binning (45-52us), 4 cells/block (49us), NTHR=1024
// (30.2us), concurrent split sweeps (28.6us, null).
__global__ void __launch_bounds__(NTHR)
la_cell3(const float* __restrict__ pts,
         const float* __restrict__ means3D,
         const float* __restrict__ opacities,
         const float* __restrict__ semantics,
         const float* __restrict__ scales,
         const float* __restrict__ cov3D,
         float* __restrict__ out) {
    __shared__ int4 sbox[BCAP];     // 4 KB
    __shared__ int  splist[PCAP];
    __shared__ int  snb, snp;

    const int t = threadIdx.x;
    const int cell = blockIdx.x;
    const int ccx = cell % NCX;
    const int ccy = cell / NCX;

    if (t == 0) { snb = 0; snp = 0; }
    __syncthreads();

    // phase 1: collect this cell's points — 4 points per iteration
    const float4* p4 = (const float4*)pts;
    for (int j = t; j < P_TOTAL / 4; j += NTHR) {
        float4 a = p4[j * 3 + 0];
        float4 b = p4[j * 3 + 1];
        float4 c = p4[j * 3 + 2];
        float pxs[4] = {a.x, a.w, b.z, c.y};
        float pys[4] = {a.y, b.x, b.w, c.z};
#pragma unroll
        for (int q = 0; q < 4; ++q) {
            int cx = ((int)((pxs[q] + 50.0f) * 2.0f)) >> CS_SH;
            int cy = ((int)((pys[q] + 50.0f) * 2.0f)) >> CS_SH;
            if (cx == ccx && cy == ccy) {
                int s = atomicAdd(&snp, 1);
                if (s < PCAP) splist[s] = j * 4 + q;
            }
        }
    }

    // phase 2: collect boxes overlapping this cell — 4 gaussians per iteration
    const float4* m4 = (const float4*)means3D;
    const float4* s4 = (const float4*)scales;
    for (int j = t; j < G_TOTAL / 4; j += NTHR) {
        float4 ma = m4[j * 3 + 0], mb = m4[j * 3 + 1], mc = m4[j * 3 + 2];
        float4 sa = s4[j * 3 + 0], sb = s4[j * 3 + 1], sc = s4[j * 3 + 2];
        float mxs[4] = {ma.x, ma.w, mb.z, mc.y};
        float mys[4] = {ma.y, mb.x, mb.w, mc.z};
        float mzs[4] = {ma.z, mb.y, mc.x, mc.w};
        float sxs[4] = {sa.x, sa.w, sb.z, sc.y};
        float sys[4] = {sa.y, sb.x, sb.w, sc.z};
        float szs[4] = {sa.z, sb.y, sc.x, sc.w};
#pragma unroll
        for (int q = 0; q < 4; ++q) {
            // (mu - PC_MIN)/0.5 == (mu - PC_MIN)*2 exactly
            int mix = (int)((mxs[q] + 50.0f) * 2.0f);
            int miy = (int)((mys[q] + 50.0f) * 2.0f);
            int miz = (int)((mzs[q] + 5.0f) * 2.0f);
            // radii = ceil(max(s)*3.0/0.5): *3.0 rounds, *2 exact
            int r = (int)ceilf((fmaxf(fmaxf(sxs[q], sys[q]), szs[q]) * 3.0f) * 2.0f);
            int w = 2 * r;
            int minx = mix - r, miny = miy - r, minz = miz - r;
            int cx0 = max(minx, 0) >> CS_SH;
            int cx1 = min(minx + w, 199) >> CS_SH;
            int cy0 = max(miny, 0) >> CS_SH;
            int cy1 = min(miny + w, 199) >> CS_SH;
            if (ccx >= cx0 && ccx <= cx1 && ccy >= cy0 && ccy <= cy1) {
                int s = atomicAdd(&snb, 1);
                if (s < BCAP)
                    sbox[s] = make_int4(minx, miny, minz, (w << 16) | (j * 4 + q));
            }
        }
    }
    __syncthreads();

    const int np = min(snp, PCAP);
    const int nb = min(snb, BCAP);
    const int wv = t >> 6, lane = t & 63;      // 8 waves per block

    // phase 3: wave-per-point gather; lanes 0..17 accumulate classes.
    for (int idx = wv; idx < np; idx += NTHR / 64) {
        int pt = splist[idx];
        float px = pts[pt * 3 + 0];
        float py = pts[pt * 3 + 1];
        float pz = pts[pt * 3 + 2];
        int pix = (int)((px + 50.0f) * 2.0f);
        int piy = (int)((py + 50.0f) * 2.0f);
        int piz = (int)((pz + 5.0f) * 2.0f);

        float acc = 0.0f;
        for (int base = 0; base < nb; base += 64) {
            int i = base + lane;
            float wgt = 0.0f;
            int gid = 0;
            if (i < nb) {
                int4 b = sbox[i];
                unsigned w  = ((unsigned)b.w) >> 16;
                unsigned ux = (unsigned)(pix - b.x);
                unsigned uy = (unsigned)(piy - b.y);
                unsigned uz = (unsigned)(piz - b.z);
                if (ux <= w && uy <= w && uz <= w) {
                    gid = b.w & 0xffff;
                    float mx = means3D[gid * 3 + 0];
                    float my = means3D[gid * 3 + 1];
                    float mz = means3D[gid * 3 + 2];
                    const float* cv = cov3D + (size_t)gid * 9;
                    float dx = px - mx, dy = py - my, dz = pz - mz;
                    float pw = -0.5f * (cv[0] * dx * dx + cv[4] * dy * dy + cv[8] * dz * dz)
                               - cv[1] * dx * dy - cv[5] * dy * dz - cv[2] * dx * dz;
                    wgt = __expf(pw) * opacities[gid];
                }
            }

            // batched hit processing: collect up to HB hits with shuffles only,
            // then issue all HB semantics loads independently (MLP ~13).
            unsigned long long m = __ballot(wgt != 0.0f);
            while (m) {
                float wh[HB];
                int   gh[HB];
#pragma unroll
                for (int k = 0; k < HB; ++k) {
                    bool has = (m != 0);
                    int h = (int)__builtin_ctzll(m | 0x8000000000000000ULL);
                    float w_ = __shfl(wgt, h, 64);   // uniform index -> readlane
                    int   g_ = __shfl(gid, h, 64);
                    wh[k] = has ? w_ : 0.0f;         // wgt=0 -> fma is identity
                    gh[k] = has ? g_ : 0;            // dummy load hits sem[0..17]
                    m &= m - 1;
                }
                if (lane < C_CLS) {
#pragma unroll
                    for (int k = 0; k < HB; ++k)
                        acc = fmaf(wh[k], semantics[(size_t)gh[k] * C_CLS + lane], acc);
                }
            }
        }

        if (lane < C_CLS)
            out[(size_t)pt * C_CLS + lane] = acc;   // coalesced 72B per point
    }
}

extern "C" void kernel_launch(void* const* d_in, const int* in_sizes, int n_in,
                              void* d_out, int out_size, void* d_ws, size_t ws_size,
                              hipStream_t stream) {
    const float* pts      = (const float*)d_in[0];
    const float* means3D  = (const float*)d_in[1];
    const float* opac     = (const float*)d_in[2];
    const float* sem      = (const float*)d_in[3];
    const float* scales   = (const float*)d_in[4];
    const float* cov3D    = (const float*)d_in[5];
    float* out = (float*)d_out;

    la_cell3<<<NCELL, NTHR, 0, stream>>>(pts, means3D, opac, sem, scales, cov3D, out);
}